// Round 1
// baseline (23452.748 us; speedup 1.0000x reference)
//
#include <hip/hip_runtime.h>

// LSTM: x(64,1024,128) fp32, W(128,2048), U(512,2048), bias(2048), fc_w(512,7), fc_b(7)
// out: (64,1,7) fp32 = h_last @ fc_w + fc_b
//
// Persistent cooperative kernel, 256 WGs x 256 threads, 1 grid barrier per timestep.
// Recurrent GEMM via bf16x3 split MFMA (16x16x32), U/W register-stationary.

#define BATCH 64
#define SEQ   1024
#define IND   128
#define HID   512
#define HBUF  (BATCH * HID)   // elements per h buffer (one time-slot)

typedef __attribute__((ext_vector_type(8))) short short8;
typedef __attribute__((ext_vector_type(4))) float f32x4;

__device__ __forceinline__ short f2bf_rne(float f) {
  unsigned u = __float_as_uint(f);
  unsigned r = u + 0x7fffu + ((u >> 16) & 1u);
  return (short)(r >> 16);
}
__device__ __forceinline__ float bf2f(short s) {
  return __uint_as_float(((unsigned)(unsigned short)s) << 16);
}

__device__ __forceinline__ void grid_barrier(unsigned* bar, unsigned nwg) {
  __syncthreads();
  if (threadIdx.x == 0) {
    unsigned gen = __hip_atomic_load(&bar[1], __ATOMIC_RELAXED, __HIP_MEMORY_SCOPE_AGENT);
    unsigned arr = __hip_atomic_fetch_add(&bar[0], 1u, __ATOMIC_ACQ_REL, __HIP_MEMORY_SCOPE_AGENT);
    if (arr == nwg - 1u) {
      __hip_atomic_store(&bar[0], 0u, __ATOMIC_RELAXED, __HIP_MEMORY_SCOPE_AGENT);
      __hip_atomic_fetch_add(&bar[1], 1u, __ATOMIC_RELEASE, __HIP_MEMORY_SCOPE_AGENT);
    } else {
      while (__hip_atomic_load(&bar[1], __ATOMIC_ACQUIRE, __HIP_MEMORY_SCOPE_AGENT) == gen) {
        __builtin_amdgcn_s_sleep(2);
      }
    }
  }
  __syncthreads();
}

// grid: 256 WGs = 4 row-blocks (16 batch rows) x 64 unit-blocks (8 hidden units)
// per WG: gates tile 16 rows x 32 gate-cols as TWO 16x16 MFMA tiles:
//   tile0 cols: [i-gate u0..u0+7 | f-gate u0..u0+7]
//   tile1 cols: [g-gate u0..u0+7 | o-gate u0..u0+7]   (gatecol = tile0col + 1024)
// K = 640 (k<512: U rows, h operand; k>=512: W rows, x_t operand), split 160/wave.
__global__ void __launch_bounds__(256, 1)
lstm_persistent(const float* __restrict__ x, const float* __restrict__ Wm,
                const float* __restrict__ Um, const float* __restrict__ bias,
                const float* __restrict__ fcw, const float* __restrict__ fcb,
                float* __restrict__ out, short* __restrict__ hhi,
                short* __restrict__ hlo, unsigned* bar) {
  const int tid = threadIdx.x;
  const int l = tid & 63;          // lane
  const int w = tid >> 6;          // wave = k-chunk (0..3)
  const int bid = blockIdx.x;
  const int rb = bid >> 6;         // 0..3 row block
  const int ub = bid & 63;         // 0..63 unit block
  const int r0 = rb * 16;
  const int u0 = ub * 8;

  const int lr = l & 15;           // MFMA row/col index within fragment
  const int lk = (l >> 4) << 3;    // MFMA k sub-offset: 0,8,16,24

  // ---- stationary B fragments (U/W slice), bf16 hi/lo -------------------
  // tile0 column map for this lane:
  const int gc0 = (lr < 8) ? (u0 + lr) : (HID + u0 + (lr - 8));
  short8 bh[5][2], bl[5][2];
#pragma unroll
  for (int s = 0; s < 5; ++s) {
    const int k0 = w * 160 + s * 32;
#pragma unroll
    for (int tile = 0; tile < 2; ++tile) {
      const int gc = gc0 + tile * 1024;
      short8 vh, vl;
#pragma unroll
      for (int j = 0; j < 8; ++j) {
        const int k = k0 + lk + j;
        const float v = (k < HID) ? Um[(size_t)k * 2048 + gc]
                                  : Wm[(size_t)(k - HID) * 2048 + gc];
        const short hi16 = f2bf_rne(v);
        vh[j] = hi16;
        vl[j] = f2bf_rne(v - bf2f(hi16));
      }
      bh[s][tile] = vh;
      bl[s][tile] = vl;
    }
  }

  // ---- elementwise-thread state (threads 0..127: (row r, unit j)) -------
  const int er = tid >> 3;  // row within block (valid < 16)
  const int ej = tid & 7;   // unit within block
  float c_state = 0.f;
  float b_i = 0.f, b_f = 0.f, b_g = 0.f, b_o = 0.f;
  if (tid < 128) {
    b_i = bias[u0 + ej];
    b_f = bias[HID + u0 + ej];
    b_g = bias[2 * HID + u0 + ej];
    b_o = bias[3 * HID + u0 + ej];
  }

  __shared__ float red[2 * 4 * 64 * 4];  // [tile][wave][lane][reg] partial gates, 8 KB
  __shared__ float pl[16 * 16 * 7];      // FC partials, 7 KB

  const int arow = r0 + lr;

  for (int t = 0; t < SEQ; ++t) {
    const int cur = t & 1;
    const short* __restrict__ hh = hhi + cur * HBUF;
    const short* __restrict__ hl = hlo + cur * HBUF;

    f32x4 acc0 = {0.f, 0.f, 0.f, 0.f};
    f32x4 acc1 = {0.f, 0.f, 0.f, 0.f};
#pragma unroll
    for (int s = 0; s < 5; ++s) {
      const int k0 = w * 160 + s * 32;
      short8 ah, al;
      if (k0 < HID) {
        const int off = arow * HID + k0 + lk;
        ah = *(const short8*)(hh + off);
        al = *(const short8*)(hl + off);
      } else {
        const int kx = k0 - HID + lk;
        const float* px = x + ((size_t)arow * SEQ + t) * IND + kx;
        const f32x4 x0 = *(const f32x4*)px;
        const f32x4 x1 = *(const f32x4*)(px + 4);
#pragma unroll
        for (int j = 0; j < 4; ++j) {
          const short h0 = f2bf_rne(x0[j]);
          ah[j] = h0;
          al[j] = f2bf_rne(x0[j] - bf2f(h0));
          const short h1 = f2bf_rne(x1[j]);
          ah[4 + j] = h1;
          al[4 + j] = f2bf_rne(x1[j] - bf2f(h1));
        }
      }
      // bf16x3: a*b ~= ah*bh + ah*bl + al*bh
      acc0 = __builtin_amdgcn_mfma_f32_16x16x32_bf16(ah, bh[s][0], acc0, 0, 0, 0);
      acc0 = __builtin_amdgcn_mfma_f32_16x16x32_bf16(ah, bl[s][0], acc0, 0, 0, 0);
      acc0 = __builtin_amdgcn_mfma_f32_16x16x32_bf16(al, bh[s][0], acc0, 0, 0, 0);
      acc1 = __builtin_amdgcn_mfma_f32_16x16x32_bf16(ah, bh[s][1], acc1, 0, 0, 0);
      acc1 = __builtin_amdgcn_mfma_f32_16x16x32_bf16(ah, bl[s][1], acc1, 0, 0, 0);
      acc1 = __builtin_amdgcn_mfma_f32_16x16x32_bf16(al, bh[s][1], acc1, 0, 0, 0);
    }

    // ---- cross-wave K reduction through LDS ----
    __syncthreads();  // red free from previous iteration
    *(f32x4*)&red[((0 * 4 + w) * 64 + l) * 4] = acc0;
    *(f32x4*)&red[((1 * 4 + w) * 64 + l) * 4] = acc1;
    __syncthreads();

    if (tid < 128) {
      // D layout: row=(lane>>4)*4+reg, col=lane&15
      const int colA = ej;          // i / g gate column
      const int colB = 8 + ej;      // f / o gate column
      const int laneA = ((er >> 2) << 4) | colA;
      const int laneB = ((er >> 2) << 4) | colB;
      const int reg = er & 3;
      float gi = b_i, gf = b_f, gg = b_g, go = b_o;
#pragma unroll
      for (int ww = 0; ww < 4; ++ww) {
        gi += red[((0 * 4 + ww) * 64 + laneA) * 4 + reg];
        gf += red[((0 * 4 + ww) * 64 + laneB) * 4 + reg];
        gg += red[((1 * 4 + ww) * 64 + laneA) * 4 + reg];
        go += red[((1 * 4 + ww) * 64 + laneB) * 4 + reg];
      }
      const float iv = 1.f / (1.f + __expf(-gi));
      const float fv = 1.f / (1.f + __expf(-gf));
      const float gv = tanhf(gg);
      const float ov = 1.f / (1.f + __expf(-go));
      c_state = fv * c_state + iv * gv;
      const float hval = ov * tanhf(c_state);
      const short hi16 = f2bf_rne(hval);
      const short lo16 = f2bf_rne(hval - bf2f(hi16));
      const int off = (cur ^ 1) * HBUF + (r0 + er) * HID + u0 + ej;
      hhi[off] = hi16;
      hlo[off] = lo16;
    }
    grid_barrier(bar, 256u);
  }

  // ---- final FC: out = h_last @ fc_w + fc_b ; h_last lives in buffer 0 ----
  if (ub == 0) {
    const int r = tid >> 4;   // 0..15
    const int kg = tid & 15;  // k-group of 32
    const int row = r0 + r;
    float p[7] = {0.f, 0.f, 0.f, 0.f, 0.f, 0.f, 0.f};
#pragma unroll 4
    for (int kk = 0; kk < 32; ++kk) {
      const int k = kg * 32 + kk;
      const float hv = bf2f(hhi[row * HID + k]) + bf2f(hlo[row * HID + k]);
      const float* fw = fcw + k * 7;
#pragma unroll
      for (int c = 0; c < 7; ++c) p[c] += hv * fw[c];
    }
#pragma unroll
    for (int c = 0; c < 7; ++c) pl[(r * 16 + kg) * 7 + c] = p[c];
    __syncthreads();
    if (tid < 112) {
      const int rr = tid / 7, cc = tid % 7;
      float s = fcb[cc];
#pragma unroll
      for (int kg2 = 0; kg2 < 16; ++kg2) s += pl[(rr * 16 + kg2) * 7 + cc];
      out[(r0 + rr) * 7 + cc] = s;
    }
  }
}

extern "C" void kernel_launch(void* const* d_in, const int* in_sizes, int n_in,
                              void* d_out, int out_size, void* d_ws, size_t ws_size,
                              hipStream_t stream) {
  const float* x = (const float*)d_in[0];
  const float* Wm = (const float*)d_in[1];
  const float* Um = (const float*)d_in[2];
  const float* bias = (const float*)d_in[3];
  const float* fcw = (const float*)d_in[4];
  const float* fcb = (const float*)d_in[5];
  float* out = (float*)d_out;

  unsigned char* ws = (unsigned char*)d_ws;
  unsigned* bar = (unsigned*)ws;                       // [counter, gen]
  short* hhi = (short*)(ws + 256);                     // 2 x 64 x 512 bf16-hi
  short* hlo = (short*)(ws + 256 + 2 * HBUF * 2);      // 2 x 64 x 512 bf16-lo

  // zero barrier state + both h double-buffers (h0 = 0); re-done every launch
  hipMemsetAsync(d_ws, 0, 256 + 2 * (2 * HBUF * 2), stream);

  void* args[] = {&x, &Wm, &Um, &bias, &fcw, &fcb, &out, &hhi, &hlo, &bar};
  hipError_t e = hipLaunchCooperativeKernel((const void*)lstm_persistent,
                                            dim3(256), dim3(256), args, 0, stream);
  if (e != hipSuccess) {
    // fallback: plain launch (256 WGs x 256 thr co-reside on 256 CUs)
    hipLaunchKernelGGL(lstm_persistent, dim3(256), dim3(256), 0, stream, x, Wm,
                       Um, bias, fcw, fcb, out, hhi, hlo, bar);
  }
}

// Round 2
// 7642.311 us; speedup vs baseline: 3.0688x; 3.0688x over previous
//
#include <hip/hip_runtime.h>

// LSTM: x(64,1024,128) fp32, W(128,2048), U(512,2048), bias(2048), fc_w(512,7), fc_b(7)
// out = (h_last @ fc_w + fc_b)  reshaped (64,1,7)
//
// 4 independent clusters (16 batch rows each) x 16 WGs (32 hidden units each).
// Per step: flag-based cluster all-gather of h (packed bf16 hi|lo u32 via L3),
// LDS-staged A operand (h + x_t), register-stationary U/W B-fragments,
// bf16x3 split MFMA 16x16x32.

#define SEQ   1024
#define IND   128
#define HID   512
#define HSLOT (64 * HID)   // u32 elems per h time-slot

typedef __attribute__((ext_vector_type(8))) short short8;
typedef __attribute__((ext_vector_type(4))) float f32x4;
typedef unsigned int uint;

__device__ __forceinline__ unsigned short f2bf(float f) {
  unsigned u = __float_as_uint(f);
  unsigned r = u + 0x7fffu + ((u >> 16) & 1u);
  return (unsigned short)(r >> 16);
}
__device__ __forceinline__ float bf2f(unsigned short s) {
  return __uint_as_float(((unsigned)s) << 16);
}

__global__ void __launch_bounds__(512, 2)
lstm_cluster(const float* __restrict__ x, const float* __restrict__ Wm,
             const float* __restrict__ Um, const float* __restrict__ bias,
             const float* __restrict__ fcw, const float* __restrict__ fcb,
             float* __restrict__ out, uint* __restrict__ hbuf,
             uint* __restrict__ flags) {
  const int tid = threadIdx.x;
  const int l   = tid & 63;
  const int wid = tid >> 6;                       // 0..7
  // bid -> (cluster, member), keeping a cluster on 2 XCDs (bid%8 ~ XCD)
  const int bid = blockIdx.x;
  const int xs  = bid & 7;
  const int cl  = xs >> 1;                        // 0..3 cluster (16 rows)
  const int mm  = ((bid >> 3) << 1) | (xs & 1);   // 0..15 member (32 units)
  const int r0  = cl * 16;
  const int ub  = mm * 32;

  __shared__ short sm_hi[16 * 640];   // A operand hi plane (rows x K), swizzled
  __shared__ short sm_lo[16 * 640];
  __shared__ float dbuf[8][64][4];    // per-wave D fragments
  __shared__ float fcp[16][32][7];    // FC partials

  // ---- stationary B fragments (U rows 0..511, then W rows as K=512..639) ----
  const int n    = wid;               // N-tile: gate g = n>>1, unit-sub = n&1
  const int g    = n >> 1;
  const int cb   = g * HID + ub + (n & 1) * 16 + (l & 15);
  const int koff = (l >> 4) * 8;
  short8 bh[20], bl[20];
#pragma unroll
  for (int s = 0; s < 20; ++s) {
    short8 vh, vl;
#pragma unroll
    for (int j = 0; j < 8; ++j) {
      const int k = s * 32 + koff + j;
      const float v = (k < HID) ? Um[(size_t)k * 2048 + cb]
                                : Wm[(size_t)(k - HID) * 2048 + cb];
      const unsigned short h16 = f2bf(v);
      vh[j] = (short)h16;
      vl[j] = (short)f2bf(v - bf2f(h16));
    }
    bh[s] = vh;
    bl[s] = vl;
  }

  // ---- elementwise identity: (row er, unit eu) ----
  const int er = tid >> 5;            // 0..15
  const int eu = tid & 31;            // 0..31
  const float b_i = bias[0 * HID + ub + eu];
  const float b_f = bias[1 * HID + ub + eu];
  const float b_g = bias[2 * HID + ub + eu];
  const float b_o = bias[3 * HID + ub + eu];
  float c_state = 0.f;

  uint* const myflag = flags + (cl * 16 + mm) * 32;       // 128B-spaced
  uint* const pollp  = flags + (cl * 16 + (l & 15)) * 32;

  const int ar    = l & 15;           // A-frag row
  const int abase = ar * 1280;        // row stride 640 shorts
  const int asw   = (ar & 7) << 4;    // XOR swizzle

  for (int t = 0; t < SEQ; ++t) {
    // ---- wait until all cluster members published h_t ----
    if (wid == 0) {
      while (true) {
        const uint v = __hip_atomic_load(pollp, __ATOMIC_RELAXED,
                                         __HIP_MEMORY_SCOPE_AGENT);
        if (__all((int)(v >= (uint)t))) break;
        __builtin_amdgcn_s_sleep(1);
      }
    }
    __syncthreads();
    __builtin_amdgcn_fence(__ATOMIC_ACQUIRE, "agent");

    // ---- stage h_t (packed u32) + x_t (fp32->bf16 pair) into LDS ----
    {
      const uint* hb = hbuf + (t & 1) * HSLOT + r0 * HID;
#pragma unroll
      for (int j = 0; j < 4; ++j) {
        const int e = (j * 512 + tid) * 4;      // 4 packed elems
        const int r = e >> 9, c = e & 511;
        const uint4 p = *(const uint4*)(hb + e);
        uint2 hw, lw;
        hw.x = (p.y & 0xFFFF0000u) | (p.x >> 16);
        hw.y = (p.w & 0xFFFF0000u) | (p.z >> 16);
        lw.x = (p.x & 0xFFFFu) | (p.y << 16);
        lw.y = (p.z & 0xFFFFu) | (p.w << 16);
        const int sb = (r * 1280 + c * 2) ^ ((r & 7) << 4);
        *(uint2*)(sm_hi + (sb >> 1)) = hw;
        *(uint2*)(sm_lo + (sb >> 1)) = lw;
      }
      {
        const int e = tid * 4;                  // x part: 2048 elems
        const int r = e >> 7, c = e & 127;
        const float4 xv = *(const float4*)(x + ((size_t)(r0 + r) * SEQ + t) * IND + c);
        unsigned short h0 = f2bf(xv.x), h1 = f2bf(xv.y),
                       h2 = f2bf(xv.z), h3 = f2bf(xv.w);
        unsigned short l0 = f2bf(xv.x - bf2f(h0)), l1 = f2bf(xv.y - bf2f(h1)),
                       l2 = f2bf(xv.z - bf2f(h2)), l3 = f2bf(xv.w - bf2f(h3));
        uint2 hw, lw;
        hw.x = (uint)h0 | ((uint)h1 << 16);
        hw.y = (uint)h2 | ((uint)h3 << 16);
        lw.x = (uint)l0 | ((uint)l1 << 16);
        lw.y = (uint)l2 | ((uint)l3 << 16);
        const int sb = (r * 1280 + (HID + c) * 2) ^ ((r & 7) << 4);
        *(uint2*)(sm_hi + (sb >> 1)) = hw;
        *(uint2*)(sm_lo + (sb >> 1)) = lw;
      }
    }
    __syncthreads();

    // ---- MFMA: 20 K-slices x bf16x3 ----
    f32x4 a0 = {0.f, 0.f, 0.f, 0.f};
    f32x4 a1 = {0.f, 0.f, 0.f, 0.f};
#pragma unroll
    for (int s = 0; s < 20; ++s) {
      const int byte = (abase + (s * 32 + koff) * 2) ^ asw;
      const short8 ah = *(const short8*)(sm_hi + (byte >> 1));
      const short8 al = *(const short8*)(sm_lo + (byte >> 1));
      if ((s & 1) == 0) {
        a0 = __builtin_amdgcn_mfma_f32_16x16x32_bf16(ah, bh[s], a0, 0, 0, 0);
        a0 = __builtin_amdgcn_mfma_f32_16x16x32_bf16(ah, bl[s], a0, 0, 0, 0);
        a0 = __builtin_amdgcn_mfma_f32_16x16x32_bf16(al, bh[s], a0, 0, 0, 0);
      } else {
        a1 = __builtin_amdgcn_mfma_f32_16x16x32_bf16(ah, bh[s], a1, 0, 0, 0);
        a1 = __builtin_amdgcn_mfma_f32_16x16x32_bf16(ah, bl[s], a1, 0, 0, 0);
        a1 = __builtin_amdgcn_mfma_f32_16x16x32_bf16(al, bh[s], a1, 0, 0, 0);
      }
    }
    *(f32x4*)&dbuf[n][l][0] = a0 + a1;
    __syncthreads();

    // ---- elementwise LSTM cell ----
    {
      const int lane = ((er >> 2) << 4) | (eu & 15);
      const int reg  = er & 3;
      const int nsub = eu >> 4;
      const float gi = b_i + dbuf[0 + nsub][lane][reg];
      const float gf = b_f + dbuf[2 + nsub][lane][reg];
      const float gg = b_g + dbuf[4 + nsub][lane][reg];
      const float go = b_o + dbuf[6 + nsub][lane][reg];
      const float iv = 1.f / (1.f + __expf(-gi));
      const float fv = 1.f / (1.f + __expf(-gf));
      const float gv = tanhf(gg);
      const float ov = 1.f / (1.f + __expf(-go));
      c_state = fv * c_state + iv * gv;
      const float hval = ov * tanhf(c_state);
      const unsigned short hh = f2bf(hval);
      const unsigned short hl = f2bf(hval - bf2f(hh));
      const uint packed = ((uint)hh << 16) | (uint)hl;
      __hip_atomic_store(hbuf + ((t + 1) & 1) * HSLOT + (r0 + er) * HID + ub + eu,
                         packed, __ATOMIC_RELAXED, __HIP_MEMORY_SCOPE_AGENT);
    }
    __syncthreads();
    if (tid == 0) {
      __hip_atomic_store(myflag, (uint)(t + 1), __ATOMIC_RELEASE,
                         __HIP_MEMORY_SCOPE_AGENT);
    }
  }

  // ---- final FC (member 0 of each cluster): out = h_last @ fc_w + fc_b ----
  if (mm == 0) {
    if (wid == 0) {
      while (true) {
        const uint v = __hip_atomic_load(pollp, __ATOMIC_RELAXED,
                                         __HIP_MEMORY_SCOPE_AGENT);
        if (__all((int)(v >= (uint)SEQ))) break;
        __builtin_amdgcn_s_sleep(1);
      }
    }
    __syncthreads();
    __builtin_amdgcn_fence(__ATOMIC_ACQUIRE, "agent");

    const uint* hb = hbuf + (SEQ & 1) * HSLOT + r0 * HID;  // slot 0
    float p[7] = {0.f, 0.f, 0.f, 0.f, 0.f, 0.f, 0.f};
#pragma unroll
    for (int kk = 0; kk < 16; ++kk) {
      const int k = eu * 16 + kk;
      const uint pk = hb[er * HID + k];
      const float hv = bf2f((unsigned short)(pk >> 16)) +
                       bf2f((unsigned short)(pk & 0xFFFFu));
      const float* fw = fcw + k * 7;
#pragma unroll
      for (int c = 0; c < 7; ++c) p[c] += hv * fw[c];
    }
#pragma unroll
    for (int c = 0; c < 7; ++c) fcp[er][eu][c] = p[c];
    __syncthreads();
    if (tid < 112) {
      const int rr = tid / 7, cc = tid % 7;
      float s = fcb[cc];
#pragma unroll
      for (int sg = 0; sg < 32; ++sg) s += fcp[rr][sg][cc];
      out[(r0 + rr) * 7 + cc] = s;
    }
  }
}

extern "C" void kernel_launch(void* const* d_in, const int* in_sizes, int n_in,
                              void* d_out, int out_size, void* d_ws, size_t ws_size,
                              hipStream_t stream) {
  const float* x    = (const float*)d_in[0];
  const float* Wm   = (const float*)d_in[1];
  const float* Um   = (const float*)d_in[2];
  const float* bias = (const float*)d_in[3];
  const float* fcw  = (const float*)d_in[4];
  const float* fcb  = (const float*)d_in[5];
  float* out = (float*)d_out;

  unsigned char* ws = (unsigned char*)d_ws;
  uint* flags = (uint*)ws;                    // 64 flags, 128B apart -> 8 KB
  uint* hbuf  = (uint*)(ws + 8192);           // 2 slots x 32768 u32 -> 256 KB

  // zero flags + both h slots (h_0 = 0); redone every launch (ws re-poisoned)
  hipMemsetAsync(d_ws, 0, 8192 + 2 * HSLOT * sizeof(uint), stream);

  hipLaunchKernelGGL(lstm_cluster, dim3(64), dim3(512), 0, stream,
                     x, Wm, Um, bias, fcw, fcb, out, hbuf, flags);
}